// Round 9
// baseline (214.090 us; speedup 1.0000x reference)
//
#include <hip/hip_runtime.h>
#include <cstdint>

typedef __attribute__((ext_vector_type(4))) int int32x4;
typedef __attribute__((ext_vector_type(16))) int int32x16;

#define GLOBAL_AS __attribute__((address_space(1)))
#define LDS_AS    __attribute__((address_space(3)))

// ---------------------------------------------------------------------------
// Kernel 0: pack int32-carried weight [N*K] (values in [-128,127]) to int8.
// ---------------------------------------------------------------------------
__global__ __launch_bounds__(256) void pack_w(
    const int* __restrict__ w32, uint32_t* __restrict__ w8_as_u32)
{
    const size_t i = (size_t)blockIdx.x * 256 + threadIdx.x; // 4 elems each
    const int4 v = ((const int4*)w32)[i];
    w8_as_u32[i] = (v.x & 0xff) | ((v.y & 0xff) << 8) |
                   ((v.z & 0xff) << 16) | ((uint32_t)(v.w & 0xff) << 24);
}

// ---------------------------------------------------------------------------
// Kernel 1: per-row dynamic symmetric int8 quantization (K=4096).
// ---------------------------------------------------------------------------
__global__ __launch_bounds__(256) void quant_rows(
    const float* __restrict__ in, int8_t* __restrict__ q,
    float* __restrict__ sa, int K)
{
    const int row = blockIdx.x;
    const float4* rp = (const float4*)(in + (size_t)row * K);
    const int t = threadIdx.x;

    float amax = 0.f;
    float4 v[4];
#pragma unroll
    for (int i = 0; i < 4; ++i) {
        v[i] = rp[t + (i << 8)];
        amax = fmaxf(amax,
               fmaxf(fmaxf(fabsf(v[i].x), fabsf(v[i].y)),
                     fmaxf(fabsf(v[i].z), fabsf(v[i].w))));
    }

#pragma unroll
    for (int off = 32; off; off >>= 1)
        amax = fmaxf(amax, __shfl_xor(amax, off));
    __shared__ float smax[4];
    if ((t & 63) == 0) smax[t >> 6] = amax;
    __syncthreads();
    amax = fmaxf(fmaxf(smax[0], smax[1]), fmaxf(smax[2], smax[3]));

    const float scale = (amax > 0.f) ? (amax / 127.f) : 1.f;
    if (t == 0) sa[row] = scale;
    const float rs = 1.f / scale;

    int* qrow = (int*)(q + (size_t)row * K);
#pragma unroll
    for (int i = 0; i < 4; ++i) {
        int a = __float2int_rn(v[i].x * rs);
        int b = __float2int_rn(v[i].y * rs);
        int c = __float2int_rn(v[i].z * rs);
        int d = __float2int_rn(v[i].w * rs);
        a = max(-128, min(127, a));
        b = max(-128, min(127, b));
        c = max(-128, min(127, c));
        d = max(-128, min(127, d));
        qrow[t + (i << 8)] = (a & 0xff) | ((b & 0xff) << 8) |
                             ((c & 0xff) << 16) | ((d & 0xff) << 24);
    }
}

// ---------------------------------------------------------------------------
// Kernel 2 (R9): int8 GEMM, 256x256 tile, 4 waves x (128x128), 32x32x32 MFMA,
// fragment-major LDS (0-conflict, R7/R8-verified), ring-4, stage-3-ahead,
// REGISTER-LEVEL PIPELINE: MFMA tile g from regs while ds_reading tile g+1
// and DMA-staging tile g+3 — no lgkm/vmcnt wait on the critical path.
//
// LDS tile (32 KiB): A region 16 KiB: off = mblk*2048 + kk*1024 + lane*16
// (fragment-major: each (mblk,kk) fragment = contiguous 1 KiB read as
// base + lane*16 -> 0 bank conflict). B region same at +16384.
//
// Staging inverse map (LDS dest linear, rule #21), 256 threads, 8 loads/thr:
//   region slot j = t + 256c (c=0..3): row = (t>>7)*32 + (t&31) + 64c,
//   col16 = ((t>>6)&1)*2 + ((t>>5)&1). Same for A and B regions.
//
// Ledger: prologue stage {0,1,2} (24 loads), vmcnt(8) -> tiles 0,1 landed,
// barrier, read frags tile 0 (set0). Iter g: read frags g+1 into other set
// (slot (g+1)&3; landed by prev boundary), stage g+3 (slot (g+3)&3),
// MFMA tile g (regs), vmcnt(8) -> g+2 landed [tail: vmcnt(0)], barrier.
// WAR: write slot (g+3)&3 last read iter g-2 (2 barriers back).
// Even/odd manual unroll -> both fragment sets statically indexed.
//
// Fragment maps (32x32 i8): A row = lane&31, k = (lane>>5)*16 + byte;
// B col = lane&31, same k. C/D: col = lane&31,
// row = (reg&3) + 8*(reg>>2) + 4*(lane>>5)  [guide-verified, dtype-indep].
// ---------------------------------------------------------------------------
__device__ __forceinline__ void async_load16(const int8_t* g, int8_t* lds) {
    __builtin_amdgcn_global_load_lds((const GLOBAL_AS char*)g,
                                     (LDS_AS char*)lds, 16, 0, 0);
}

__global__ __launch_bounds__(256, 1) void w8a8_gemm(
    const int8_t* __restrict__ Aq, const int8_t* __restrict__ W,
    const float* __restrict__ sa, const float* __restrict__ wsc,
    const float* __restrict__ bias, float* __restrict__ out,
    int M, int N, int K)
{
    __shared__ int8_t lds[4 * 32768]; // 128 KiB

    const int NB = N >> 8; // N/256
    const int nwg = gridDim.x;
    // XCD-aware swizzle (nwg % 8 == 0 -> bijective)
    const int cpx = nwg >> 3;
    const int wg = (blockIdx.x & 7) * cpx + (blockIdx.x >> 3);
    const int bm = wg / NB, bn = wg % NB;

    const int t = threadIdx.x;          // 0..255, 4 waves
    const int lane = t & 63, wid = t >> 6;
    const int wr = wid >> 1, wc = wid & 1;   // 2x2 wave grid, 128x128 each
    const int l31 = lane & 31, h = lane >> 5;

    // ---- staging: fragment-major inverse map, 8 loads/thread/tile ----
    const int srow = ((t >> 7) & 1) * 32 + (t & 31);          // 0..63
    const int scol = ((((t >> 6) & 1) * 2 + ((t >> 5) & 1)) << 4);
    const int8_t* gA = Aq + ((size_t)bm * 256 + srow) * (size_t)K + scol;
    const int8_t* gB = W  + ((size_t)bn * 256 + srow) * (size_t)K + scol;
    const size_t cstep = (size_t)64 * K;   // +64 rows per c
    int8_t* ldsw = &lds[t * 16];

    auto stage_tile = [&](int slot, int kbyte) {
        int8_t* d = ldsw + slot * 32768;
#pragma unroll
        for (int c = 0; c < 4; ++c) {
            async_load16(gA + c * cstep + kbyte, d + c * 4096);
            async_load16(gB + c * cstep + kbyte, d + 16384 + c * 4096);
        }
    };

    // ---- fragment read bases (contiguous: base + lane*16) ----
    const int aoff = wr * 8192 + lane * 16;          // + m*2048 (+1024 for kk1)
    const int boff = 16384 + wc * 8192 + lane * 16;  // + n*2048 (+1024 for kk1)

    auto read_frags = [&](int slot, int32x4 (&A0)[4], int32x4 (&A1)[4],
                          int32x4 (&B0)[4], int32x4 (&B1)[4]) {
        const int tb = slot * 32768;
#pragma unroll
        for (int m = 0; m < 4; ++m) {
            A0[m] = *(const int32x4*)&lds[tb + aoff + m * 2048];
            A1[m] = *(const int32x4*)&lds[tb + aoff + m * 2048 + 1024];
        }
#pragma unroll
        for (int n = 0; n < 4; ++n) {
            B0[n] = *(const int32x4*)&lds[tb + boff + n * 2048];
            B1[n] = *(const int32x4*)&lds[tb + boff + n * 2048 + 1024];
        }
    };

    int32x16 acc[4][4];
#pragma unroll
    for (int m = 0; m < 4; ++m)
#pragma unroll
        for (int n = 0; n < 4; ++n)
#pragma unroll
            for (int rgi = 0; rgi < 16; ++rgi)
                acc[m][n][rgi] = 0;

    const int NT = K >> 6; // 64 K-tiles

    int32x4 xa0[4], xa1[4], xb0[4], xb1[4]; // set X
    int32x4 ya0[4], ya1[4], yb0[4], yb1[4]; // set Y

    // prologue: stage tiles 0,1,2; tiles 0,1 landed; read frags tile 0
    stage_tile(0, 0);
    stage_tile(1, 64);
    stage_tile(2, 128);
    asm volatile("s_waitcnt vmcnt(8)" ::: "memory");
    asm volatile("s_barrier" ::: "memory");
    read_frags(0, xa0, xa1, xb0, xb1);

#define ITER_BODY(G, CA0, CA1, CB0, CB1, NA0, NA1, NB0, NB1)                   \
    {                                                                          \
        const int g_ = (G);                                                    \
        if (g_ + 1 < NT) read_frags((g_ + 1) & 3, NA0, NA1, NB0, NB1);         \
        if (g_ + 3 < NT) stage_tile((g_ + 3) & 3, (g_ + 3) << 6);              \
        _Pragma("unroll")                                                      \
        for (int m = 0; m < 4; ++m)                                            \
            _Pragma("unroll")                                                  \
            for (int n = 0; n < 4; ++n)                                        \
                acc[m][n] = __builtin_amdgcn_mfma_i32_32x32x32_i8(             \
                    CA0[m], CB0[n], acc[m][n], 0, 0, 0);                       \
        _Pragma("unroll")                                                      \
        for (int m = 0; m < 4; ++m)                                            \
            _Pragma("unroll")                                                  \
            for (int n = 0; n < 4; ++n)                                        \
                acc[m][n] = __builtin_amdgcn_mfma_i32_32x32x32_i8(             \
                    CA1[m], CB1[n], acc[m][n], 0, 0, 0);                       \
        if (g_ + 3 < NT)                                                       \
            asm volatile("s_waitcnt vmcnt(8)" ::: "memory");                   \
        else                                                                   \
            asm volatile("s_waitcnt vmcnt(0)" ::: "memory");                   \
        asm volatile("s_barrier" ::: "memory");                                \
    }

    for (int g = 0; g < NT; g += 2) {
        ITER_BODY(g,     xa0, xa1, xb0, xb1, ya0, ya1, yb0, yb1);
        ITER_BODY(g + 1, ya0, ya1, yb0, yb1, xa0, xa1, xb0, xb1);
    }
#undef ITER_BODY

    // ---- epilogue: C/D col = lane&31, row = (reg&3)+8*(reg>>2)+4*h ----
    const int col0 = bn * 256 + wc * 128 + l31;      // + n*32
    const int row00 = bm * 256 + wr * 128 + 4 * h;   // + m*32 + (reg&3)+8*(reg>>2)

#pragma unroll
    for (int m = 0; m < 4; ++m) {
        float sv[16];
#pragma unroll
        for (int rgi = 0; rgi < 16; ++rgi)
            sv[rgi] = sa[row00 + m * 32 + (rgi & 3) + 8 * (rgi >> 2)];
#pragma unroll
        for (int n = 0; n < 4; ++n) {
            const int col = col0 + n * 32;
            const float wn = wsc[col];
            const float bb = bias[col];
#pragma unroll
            for (int rgi = 0; rgi < 16; ++rgi) {
                const int row = row00 + m * 32 + (rgi & 3) + 8 * (rgi >> 2);
                out[(size_t)row * N + col] =
                    (float)acc[m][n][rgi] * sv[rgi] * wn + bb;
            }
        }
    }
}

// ---------------------------------------------------------------------------
extern "C" void kernel_launch(void* const* d_in, const int* in_sizes, int n_in,
                              void* d_out, int out_size, void* d_ws, size_t ws_size,
                              hipStream_t stream) {
    const float* inp  = (const float*)d_in[0];
    const int*   w32  = (const int*)d_in[1];   // int8 values carried as int32
    const float* wsc  = (const float*)d_in[2];
    const float* bias = (const float*)d_in[3];
    float* out = (float*)d_out;

    const int N = in_sizes[2];            // 4096
    const int K = in_sizes[1] / N;        // 4096
    const int M = in_sizes[0] / K;        // 8192

    // workspace: q[M*K] i8 | sa[M] f32 | W8[N*K] i8
    int8_t* q  = (int8_t*)d_ws;
    float*  sa = (float*)((char*)d_ws + (size_t)M * K);
    int8_t* w8 = (int8_t*)((char*)d_ws + (size_t)M * K + (size_t)M * 4 + 256);

    const size_t nw4 = ((size_t)N * K) / 4;
    pack_w<<<(int)(nw4 / 256), 256, 0, stream>>>(w32, (uint32_t*)w8);

    quant_rows<<<M, 256, 0, stream>>>(inp, q, sa, K);

    const int nwg = (M / 256) * (N / 256); // 512
    w8a8_gemm<<<nwg, 256, 0, stream>>>(q, w8, sa, wsc, bias, out, M, N, K);
}

// Round 10
// 201.829 us; speedup vs baseline: 1.0608x; 1.0608x over previous
//
#include <hip/hip_runtime.h>
#include <cstdint>

typedef __attribute__((ext_vector_type(4))) int int32x4;
typedef __attribute__((ext_vector_type(16))) int int32x16;

#define GLOBAL_AS __attribute__((address_space(1)))
#define LDS_AS    __attribute__((address_space(3)))

// ---------------------------------------------------------------------------
// Kernel 0: pack int32-carried weight [N*K] (values in [-128,127]) to int8.
// ---------------------------------------------------------------------------
__global__ __launch_bounds__(256) void pack_w(
    const int* __restrict__ w32, uint32_t* __restrict__ w8_as_u32)
{
    const size_t i = (size_t)blockIdx.x * 256 + threadIdx.x; // 4 elems each
    const int4 v = ((const int4*)w32)[i];
    w8_as_u32[i] = (v.x & 0xff) | ((v.y & 0xff) << 8) |
                   ((v.z & 0xff) << 16) | ((uint32_t)(v.w & 0xff) << 24);
}

// ---------------------------------------------------------------------------
// Kernel 1: per-row dynamic symmetric int8 quantization (K=4096).
// ---------------------------------------------------------------------------
__global__ __launch_bounds__(256) void quant_rows(
    const float* __restrict__ in, int8_t* __restrict__ q,
    float* __restrict__ sa, int K)
{
    const int row = blockIdx.x;
    const float4* rp = (const float4*)(in + (size_t)row * K);
    const int t = threadIdx.x;

    float amax = 0.f;
    float4 v[4];
#pragma unroll
    for (int i = 0; i < 4; ++i) {
        v[i] = rp[t + (i << 8)];
        amax = fmaxf(amax,
               fmaxf(fmaxf(fabsf(v[i].x), fabsf(v[i].y)),
                     fmaxf(fabsf(v[i].z), fabsf(v[i].w))));
    }

#pragma unroll
    for (int off = 32; off; off >>= 1)
        amax = fmaxf(amax, __shfl_xor(amax, off));
    __shared__ float smax[4];
    if ((t & 63) == 0) smax[t >> 6] = amax;
    __syncthreads();
    amax = fmaxf(fmaxf(smax[0], smax[1]), fmaxf(smax[2], smax[3]));

    const float scale = (amax > 0.f) ? (amax / 127.f) : 1.f;
    if (t == 0) sa[row] = scale;
    const float rs = 1.f / scale;

    int* qrow = (int*)(q + (size_t)row * K);
#pragma unroll
    for (int i = 0; i < 4; ++i) {
        int a = __float2int_rn(v[i].x * rs);
        int b = __float2int_rn(v[i].y * rs);
        int c = __float2int_rn(v[i].z * rs);
        int d = __float2int_rn(v[i].w * rs);
        a = max(-128, min(127, a));
        b = max(-128, min(127, b));
        c = max(-128, min(127, c));
        d = max(-128, min(127, d));
        qrow[t + (i << 8)] = (a & 0xff) | ((b & 0xff) << 8) |
                             ((c & 0xff) << 16) | ((d & 0xff) << 24);
    }
}

// ---------------------------------------------------------------------------
// Kernel 2 (R10): R6 structure (best measured: 156 us, MfmaUtil 40%) plus:
//   - square 8x8 XCD chunks (per-XCD footprint A 8MB + B 8MB vs strip's
//     4+16 -> FETCH ~160 -> ~128 MB, better L2 residency)
//   - stage issued at loop TOP (issue-early, max DMA latency margin)
//
// Geometry: 256x256 tile, 4 waves x (128x128), mfma_i32_32x32x32_i8,
// ONE phase / ONE vmcnt(8) / ONE barrier per K-tile, ring-4 LDS (32 KiB
// K-tiles), stage-2-ahead. Swizzle: 16B-slot s of row r holds global slot
// s ^ P(r), P(r)=((r>>1)^(r>>3))&3, applied on gload_lds GLOBAL source
// (LDS dest linear, rule #21) and on ds_read address.
//
// Ledger: prologue stages tiles 0,1 (16 loads); vmcnt(8) -> tile0 landed;
// barrier. Iter g: stage tile g+2 (8 loads) into ring (g+2)&3; 16 ds_read
// of tile g; 32 MFMA; vmcnt(8) -> tile g+1 landed (g+2 in flight)
// [tail: vmcnt(0)]; barrier. WAR: slot (g+2)&3 last read iter g-2.
//
// Fragment maps (32x32 i8): A row = lane&31, k = (lane>>5)*16 + byte;
// B col = lane&31, same k. C/D: col = lane&31,
// row = (reg&3) + 8*(reg>>2) + 4*(lane>>5)  [guide-verified, dtype-indep].
// ---------------------------------------------------------------------------
__device__ __forceinline__ void async_load16(const int8_t* g, int8_t* lds) {
    __builtin_amdgcn_global_load_lds((const GLOBAL_AS char*)g,
                                     (LDS_AS char*)lds, 16, 0, 0);
}

__global__ __launch_bounds__(256, 1) void w8a8_gemm(
    const int8_t* __restrict__ Aq, const int8_t* __restrict__ W,
    const float* __restrict__ sa, const float* __restrict__ wsc,
    const float* __restrict__ bias, float* __restrict__ out,
    int M, int N, int K)
{
    __shared__ int8_t lds[4 * 32768]; // 128 KiB

    const int MB = M >> 8, NB = N >> 8;
    int bm, bn;
    if (MB == 32 && NB == 16) {
        // square XCD swizzle: XCD x = bid&7 owns an 8x8 tile square
        const int x = blockIdx.x & 7, i = blockIdx.x >> 3;
        bm = ((x >> 1) << 3) + (i >> 3);
        bn = ((x & 1) << 3) + (i & 7);
    } else {
        const int cpx = gridDim.x >> 3;
        const int wg = (blockIdx.x & 7) * cpx + (blockIdx.x >> 3);
        bm = wg / NB; bn = wg % NB;
    }

    const int t = threadIdx.x;          // 0..255, 4 waves
    const int lane = t & 63, wid = t >> 6;
    const int wr = wid >> 1, wc = wid & 1;   // 2x2 wave grid, 128x128 each
    const int l31 = lane & 31, h = lane >> 5;
    const int pswz = ((lane >> 1) ^ (lane >> 3)) & 3;

    // ---- staging: thread t covers chunk slots t and t+256 ----
    const int srow = t >> 2;            // 0..63
    const int scol = (((t & 3) ^ ((t >> 3) & 3) ^ ((t >> 5) & 3)) << 4);
    const int8_t* gA = Aq + ((size_t)bm * 256 + srow) * (size_t)K + scol;
    const int8_t* gB = W  + ((size_t)bn * 256 + srow) * (size_t)K + scol;
    const size_t rstep = (size_t)64 * K;   // slot t+256: +64 rows
    const size_t hstep = (size_t)128 * K;  // chunk half: +128 rows
    int8_t* ldsw = &lds[t * 16];

    auto stage_tile = [&](int slot, int kbyte) {
#pragma unroll
        for (int c = 0; c < 4; ++c) {
            const int8_t* s0 = (c < 2 ? gA : gB) + (size_t)(c & 1) * hstep + kbyte;
            int8_t* d0 = ldsw + slot * 32768 + (c >> 1) * 16384 + (c & 1) * 8192;
            async_load16(s0, d0);
            async_load16(s0 + rstep, d0 + 4096);
        }
    };

    // ---- fragment read bases (swizzled) ----
    const int aoff = wr * 8192 + l31 * 64;          // + m*2048 + cs
    const int boff = 16384 + wc * 8192 + l31 * 64;  // + n*2048 + cs
    const int cs0 = ((0 + h) ^ pswz) << 4;          // kk = 0
    const int cs1 = ((2 + h) ^ pswz) << 4;          // kk = 1

    int32x16 acc[4][4];
#pragma unroll
    for (int m = 0; m < 4; ++m)
#pragma unroll
        for (int n = 0; n < 4; ++n)
#pragma unroll
            for (int rgi = 0; rgi < 16; ++rgi)
                acc[m][n][rgi] = 0;

    const int NT = K >> 6; // 64 K-tiles

    // prologue: stage K-tiles 0 (ring 0) and 1 (ring 1)
    stage_tile(0, 0);
    stage_tile(1, 64);
    asm volatile("s_waitcnt vmcnt(8)" ::: "memory");
    asm volatile("s_barrier" ::: "memory");

    for (int g = 0; g < NT; ++g) {
        const int rbase = (g & 3) * 32768;

        // issue-early DMA for tile g+2
        if (g + 2 < NT) stage_tile((g + 2) & 3, (g + 2) << 6);

        int32x4 a0[4], b0[4], a1[4], b1[4];
#pragma unroll
        for (int m = 0; m < 4; ++m)
            a0[m] = *(const int32x4*)&lds[rbase + aoff + m * 2048 + cs0];
#pragma unroll
        for (int n = 0; n < 4; ++n)
            b0[n] = *(const int32x4*)&lds[rbase + boff + n * 2048 + cs0];
#pragma unroll
        for (int m = 0; m < 4; ++m)
            a1[m] = *(const int32x4*)&lds[rbase + aoff + m * 2048 + cs1];
#pragma unroll
        for (int n = 0; n < 4; ++n)
            b1[n] = *(const int32x4*)&lds[rbase + boff + n * 2048 + cs1];

#pragma unroll
        for (int m = 0; m < 4; ++m)
#pragma unroll
            for (int n = 0; n < 4; ++n)
                acc[m][n] = __builtin_amdgcn_mfma_i32_32x32x32_i8(
                    a0[m], b0[n], acc[m][n], 0, 0, 0);
#pragma unroll
        for (int m = 0; m < 4; ++m)
#pragma unroll
            for (int n = 0; n < 4; ++n)
                acc[m][n] = __builtin_amdgcn_mfma_i32_32x32x32_i8(
                    a1[m], b1[n], acc[m][n], 0, 0, 0);

        if (g < NT - 2)
            asm volatile("s_waitcnt vmcnt(8)" ::: "memory");
        else
            asm volatile("s_waitcnt vmcnt(0)" ::: "memory");
        asm volatile("s_barrier" ::: "memory");
    }

    // ---- epilogue: C/D col = lane&31, row = (reg&3)+8*(reg>>2)+4*h ----
    const int col0 = bn * 256 + wc * 128 + l31;      // + n*32
    const int row00 = bm * 256 + wr * 128 + 4 * h;   // + m*32 + (reg&3)+8*(reg>>2)

#pragma unroll
    for (int m = 0; m < 4; ++m) {
        float sv[16];
#pragma unroll
        for (int rgi = 0; rgi < 16; ++rgi)
            sv[rgi] = sa[row00 + m * 32 + (rgi & 3) + 8 * (rgi >> 2)];
#pragma unroll
        for (int n = 0; n < 4; ++n) {
            const int col = col0 + n * 32;
            const float wn = wsc[col];
            const float bb = bias[col];
#pragma unroll
            for (int rgi = 0; rgi < 16; ++rgi) {
                const int row = row00 + m * 32 + (rgi & 3) + 8 * (rgi >> 2);
                out[(size_t)row * N + col] =
                    (float)acc[m][n][rgi] * sv[rgi] * wn + bb;
            }
        }
    }
}

// ---------------------------------------------------------------------------
extern "C" void kernel_launch(void* const* d_in, const int* in_sizes, int n_in,
                              void* d_out, int out_size, void* d_ws, size_t ws_size,
                              hipStream_t stream) {
    const float* inp  = (const float*)d_in[0];
    const int*   w32  = (const int*)d_in[1];   // int8 values carried as int32
    const float* wsc  = (const float*)d_in[2];
    const float* bias = (const float*)d_in[3];
    float* out = (float*)d_out;

    const int N = in_sizes[2];            // 4096
    const int K = in_sizes[1] / N;        // 4096
    const int M = in_sizes[0] / K;        // 8192

    // workspace: q[M*K] i8 | sa[M] f32 | W8[N*K] i8
    int8_t* q  = (int8_t*)d_ws;
    float*  sa = (float*)((char*)d_ws + (size_t)M * K);
    int8_t* w8 = (int8_t*)((char*)d_ws + (size_t)M * K + (size_t)M * 4 + 256);

    const size_t nw4 = ((size_t)N * K) / 4;
    pack_w<<<(int)(nw4 / 256), 256, 0, stream>>>(w32, (uint32_t*)w8);

    quant_rows<<<M, 256, 0, stream>>>(inp, q, sa, K);

    const int nwg = (M / 256) * (N / 256); // 512
    w8a8_gemm<<<nwg, 256, 0, stream>>>(q, w8, sa, wsc, bias, out, M, N, K);
}